// Round 12
// baseline (48.320 us; speedup 1.0000x reference)
//
#include <hip/hip_runtime.h>
#include <hip/hip_bf16.h>

// RippleNetPlus fused — 1 block (256 thr) per TWO batch elements.
// DIM=32, HOP=2, MEM=32, BATCH=2048 -> grid 1024 = exactly 4 blocks/CU.
//
// Round 12: latency-hiding via free registers. Grid gives 4 blocks/CU ->
// VGPR<=128 costs nothing (LDS 29.2KB x4 = 117KB). R11 PMC: VALU 34%,
// ~2/3 stall, dominated by phase A's unroll-1 8-iteration gather chain.
//  - phase A: 4 iterations, each processing 4 independent (elem x hop)
//    streams -> 2x loads in flight, serial chain halved.
//  - t-rows (both hops) prefetched BEFORE phase A (latency hides under A).
//  - B-fragments (bv) hoisted out of the hop loop (hop-invariant).
//  - hop loop #pragma unroll -> tv static indexing (no scratch).
// Phase bodies otherwise = R11 (verified absmax 0).

#define NHOP 2

typedef __attribute__((ext_vector_type(4)))  float f32x4;
typedef __attribute__((ext_vector_type(8)))  short bf16x8s;
typedef __attribute__((ext_vector_type(4)))  int   i32x4;

__device__ __forceinline__ float sigmoid_f(float x){ return 1.0f/(1.0f+__expf(-x)); }
__device__ __forceinline__ float tanh_f(float x){
  float e = __expf(2.0f*x);
  return 1.0f - 2.0f/(e + 1.0f);
}
__device__ __forceinline__ unsigned pk_bf16(float lo, float hi){
  __hip_bfloat162 h = __float22bfloat162_rn(make_float2(lo, hi));
  return *reinterpret_cast<unsigned*>(&h);
}

__global__ __launch_bounds__(256) void ripple_fused(
    const int* __restrict__ h_i, const int* __restrict__ R_i, const int* __restrict__ t_i,
    const int* __restrict__ v_i,
    const float* __restrict__ entity_emb, const float* __restrict__ relation_emb,
    const float* __restrict__ agg_w1, const float* __restrict__ agg_b1,
    const float* __restrict__ agg_w2, const float* __restrict__ agg_b2,
    const float* __restrict__ gru_w_ih, const float* __restrict__ gru_w_hh,
    const float* __restrict__ gru_b_ih, const float* __restrict__ gru_b_hh,
    const float* __restrict__ ans_w, const float* __restrict__ ans_b,
    float* __restrict__ out, int batch)
{
  __shared__ __align__(16) int   s_bfrag[8*64*4];     // 8 KB   shared B-frags
  __shared__ __align__(16) float s_rhA[2][2][32*33];  // 16.5KB [elem][hop] stride-33
  __shared__ __align__(16) float s_vsM[2][64];        // [elem][i*2+{vs,M}]
  __shared__ __align__(16) float s_zpart[2][64];      // [elem][ot*32+m]
  __shared__ __align__(16) float s_opart[2][4*32];    // [elem][w][o]
  __shared__ __align__(16) float s_M[2][32];
  __shared__ __align__(16) float s_gig[2][192];       // [elem] gi[0:96] gh[96:192]

  const int bid = blockIdx.x;
  const int eA  = bid*2;
  const int eB  = (eA + 1 < batch) ? eA + 1 : eA;
  const int tid = threadIdx.x;
  const int g   = tid >> 5;   // group 0..7
  const int o   = tid & 31;
  const int l   = tid & 63;   // lane
  const int w   = tid >> 6;   // wave 0..3
  const int c   = o & 7;
  const int r_  = o >> 3;
  const bool bb4 = (c & 4) != 0;
  const bool bb2 = (c & 2) != 0;
  const bool bb1 = (c & 1) != 0;

  // ---- init: stage B-fragments (16x16x32 layout; same as R10/R11) ----
  #pragma unroll
  for (int k = 0; k < 2; ++k){
    int s  = tid + k*256;           // 0..511
    int f  = s >> 6, li = s & 63;
    int x  = f >> 1, otf = f & 1;
    const float* src = agg_w1 + (otf*16 + (li & 15))*128 + x*32 + ((li >> 4) & 3)*8;
    float4 f0 = *(const float4*)src;
    float4 f1 = *(const float4*)(src + 4);
    *(int4*)&s_bfrag[s*4] = make_int4((int)pk_bf16(f0.x, f0.y), (int)pk_bf16(f0.z, f0.w),
                                      (int)pk_bf16(f1.x, f1.y), (int)pk_bf16(f1.z, f1.w));
  }
  if (tid < 64){
    int e  = tid >> 5, oo = tid & 31;
    float v = entity_emb[(size_t)v_i[e ? eB : eA]*32 + oo];
    s_vsM[e][oo*2+0] = v; s_vsM[e][oo*2+1] = v; s_M[e][oo] = v;
  }

  // ---- t-row prefetch, both hops x both elems (consumed in phase C;
  //      issued here so the gather latency hides under phase A) ----
  float tv[2][2][4];   // [elem][hop][ml] — all statically indexed
  #pragma unroll
  for (int e = 0; e < 2; ++e){
    const int eidx = e ? eB : eA;
    #pragma unroll
    for (int hp = 0; hp < 2; ++hp){
      #pragma unroll
      for (int ml = 0; ml < 4; ++ml)
        tv[e][hp][ml] =
          entity_emb[(size_t)t_i[(eidx*NHOP + hp)*32 + g*4 + ml]*32 + o];
    }
  }

  // ---- phase A: 4 iterations x 4 independent (elem,hop) streams ----
  {
    const int iA = c*4 + r_;
    #pragma unroll 1
    for (int ml = 0; ml < 4; ++ml){
      const int m = g*4 + ml;
      const float* Rb[4];
      float4 hv[4];
      #pragma unroll
      for (int s = 0; s < 4; ++s){
        int e  = s & 1, hp = s >> 1;
        int eidx = e ? eB : eA;
        int ri = R_i[(eidx*NHOP + hp)*32 + m];
        int hi = h_i[(eidx*NHOP + hp)*32 + m];
        Rb[s]  = relation_emb + (size_t)ri*1024;
        hv[s]  = *(const float4*)(entity_emb + (size_t)hi*32 + c*4);
      }
      float p[4][8];
      #pragma unroll
      for (int s = 0; s < 4; ++s){
        #pragma unroll
        for (int q = 0; q < 8; ++q){
          float4 rv = *(const float4*)(Rb[s] + q*128 + o*4);
          p[s][q] = rv.x*hv[s].x + rv.y*hv[s].y + rv.z*hv[s].z + rv.w*hv[s].w;
        }
      }
      #pragma unroll
      for (int s = 0; s < 4; ++s){
        #pragma unroll
        for (int k = 0; k < 4; ++k){
          float send = bb4 ? p[s][k] : p[s][k+4];
          float t = __shfl_xor(send, 4);
          p[s][k] = (bb4 ? p[s][k+4] : p[s][k]) + t;
        }
        #pragma unroll
        for (int k = 0; k < 2; ++k){
          float send = bb2 ? p[s][k] : p[s][k+2];
          float t = __shfl_xor(send, 2);
          p[s][k] = (bb2 ? p[s][k+2] : p[s][k]) + t;
        }
        float send = bb1 ? p[s][0] : p[s][1];
        float t = __shfl_xor(send, 1);
        float a = (bb1 ? p[s][1] : p[s][0]) + t;
        s_rhA[s & 1][s >> 1][m*33 + iA] = a;
      }
    }
  }
  __syncthreads();

  // per-wave tile coords (phase B) + hop-invariant B-fragments in registers
  const int mt  = w >> 1, ot = w & 1;
  const int col = l & 15;
  const int kg  = l >> 4;
  const float b1o = agg_b1[ot*16 + col];
  const float w2o = agg_w2[ot*16 + col];
  i32x4 bv[4];
  #pragma unroll
  for (int x = 0; x < 4; ++x)
    bv[x] = *(const i32x4*)&s_bfrag[((x*2 + ot)*64 + l)*4];

  #pragma unroll
  for (int hop = 0; hop < NHOP; ++hop){
    // ---- phase B: wave tile via mfma_16x16x32, both elements ----
    {
      #pragma unroll
      for (int e = 0; e < 2; ++e){
        const float* rp = &s_rhA[e][hop][(mt*16 + col)*33 + kg*8];
        float4 q0 = *(const float4*)(rp);
        float4 q1 = *(const float4*)(rp + 4);
        float rh[8] = {q0.x,q0.y,q0.z,q0.w,q1.x,q1.y,q1.z,q1.w};
        unsigned aw[4][4];
        #pragma unroll
        for (int q = 0; q < 4; ++q){
          int i0 = kg*8 + 2*q;
          float2 vm0 = *(const float2*)&s_vsM[e][i0*2];
          float2 vm1 = *(const float2*)&s_vsM[e][(i0+1)*2];
          float e0 = rh[2*q], e1 = rh[2*q+1];
          aw[0][q] = pk_bf16(e0*vm0.x,        e1*vm1.x);
          aw[1][q] = pk_bf16(e0*vm0.y,        e1*vm1.y);
          aw[2][q] = pk_bf16(fabsf(e0-vm0.x), fabsf(e1-vm1.x));
          aw[3][q] = pk_bf16(fabsf(e0-vm0.y), fabsf(e1-vm1.y));
        }
        f32x4 acc = {0.f, 0.f, 0.f, 0.f};
        #pragma unroll
        for (int x = 0; x < 4; ++x){
          i32x4 av = {(int)aw[x][0], (int)aw[x][1], (int)aw[x][2], (int)aw[x][3]};
          acc = __builtin_amdgcn_mfma_f32_16x16x32_bf16(
                  __builtin_bit_cast(bf16x8s, av),
                  __builtin_bit_cast(bf16x8s, bv[x]), acc, 0, 0, 0);
        }
        float v[4];
        #pragma unroll
        for (int r = 0; r < 4; ++r) v[r] = tanh_f(acc[r] + b1o) * w2o;
        const bool b3 = (l & 8) != 0;
        #pragma unroll
        for (int k = 0; k < 2; ++k){
          float send = b3 ? v[k] : v[k+2];
          float tt = __shfl_xor(send, 8);
          v[k] = (b3 ? v[k+2] : v[k]) + tt;
        }
        const bool b2_ = (l & 4) != 0;
        {
          float send = b2_ ? v[0] : v[1];
          float tt = __shfl_xor(send, 4);
          v[0] = (b2_ ? v[1] : v[0]) + tt;
        }
        v[0] += __shfl_xor(v[0], 2);
        v[0] += __shfl_xor(v[0], 1);
        if ((l & 3) == 0){
          int m_local = kg*4 + ((l >> 3) & 1)*2 + ((l >> 2) & 1);
          s_zpart[e][ot*32 + mt*16 + m_local] = v[0];
        }
      }
    }
    __syncthreads();

    // ---- phase C: softmax (all lanes) + weighted-t, both elements ----
    #pragma unroll
    for (int e = 0; e < 2; ++e){
      float z  = s_zpart[e][o] + s_zpart[e][32 + o];
      float mx = z;
      #pragma unroll
      for (int s = 16; s > 0; s >>= 1) mx = fmaxf(mx, __shfl_xor(mx, s));
      float ex = __expf(z - mx);
      float sm = ex;
      #pragma unroll
      for (int s = 16; s > 0; s >>= 1) sm += __shfl_xor(sm, s);
      float gval = ex / sm;
      float po = 0.f;
      #pragma unroll
      for (int ml = 0; ml < 4; ++ml)
        po += __shfl(gval, g*4 + ml) * tv[e][hop][ml];
      po += __shfl_xor(po, 32);
      if (l < 32) s_opart[e][w*32 + o] = po;
    }
    __syncthreads();

    // ---- phase D: GRU gates, weights loaded once for both elements ----
    {
      const int cc = (tid & 7) * 4;
      const int rr = tid >> 3;
      float4 oA = make_float4(0,0,0,0), oB = make_float4(0,0,0,0);
      #pragma unroll
      for (int gg = 0; gg < 4; ++gg){
        float4 ta = *(const float4*)&s_opart[0][gg*32 + cc];
        float4 tb = *(const float4*)&s_opart[1][gg*32 + cc];
        oA.x += ta.x; oA.y += ta.y; oA.z += ta.z; oA.w += ta.w;
        oB.x += tb.x; oB.y += tb.y; oB.z += tb.z; oB.w += tb.w;
      }
      float4 mA = *(const float4*)&s_M[0][cc];
      float4 mB = *(const float4*)&s_M[1][cc];
      #pragma unroll
      for (int k = 0; k < 3; ++k){
        int row = k*32 + rr;
        float4 wi = *(const float4*)(gru_w_ih + ((size_t)hop*96 + row)*32 + cc);
        float4 wh = *(const float4*)(gru_w_hh + ((size_t)hop*96 + row)*32 + cc);
        float aiA = wi.x*oA.x + wi.y*oA.y + wi.z*oA.z + wi.w*oA.w;
        float ahA = wh.x*mA.x + wh.y*mA.y + wh.z*mA.z + wh.w*mA.w;
        float aiB = wi.x*oB.x + wi.y*oB.y + wi.z*oB.z + wi.w*oB.w;
        float ahB = wh.x*mB.x + wh.y*mB.y + wh.z*mB.z + wh.w*mB.w;
        aiA += __shfl_xor(aiA,1); aiA += __shfl_xor(aiA,2); aiA += __shfl_xor(aiA,4);
        ahA += __shfl_xor(ahA,1); ahA += __shfl_xor(ahA,2); ahA += __shfl_xor(ahA,4);
        aiB += __shfl_xor(aiB,1); aiB += __shfl_xor(aiB,2); aiB += __shfl_xor(aiB,4);
        ahB += __shfl_xor(ahB,1); ahB += __shfl_xor(ahB,2); ahB += __shfl_xor(ahB,4);
        if ((tid & 7) == 0){
          s_gig[0][row]      = aiA;
          s_gig[0][96 + row] = ahA;
          s_gig[1][row]      = aiB;
          s_gig[1][96 + row] = ahB;
        }
      }
    }
    __syncthreads();

    // ---- phase E: GRU update — lanes 0-31 elem A, 32-63 elem B ----
    if (tid < 64){
      int e = tid >> 5, oo = tid & 31;
      const float* bih = gru_b_ih + hop*96;
      const float* bhh = gru_b_hh + hop*96;
      float ir = s_gig[e][oo]       + bih[oo];
      float iz = s_gig[e][32 + oo]  + bih[32 + oo];
      float in_= s_gig[e][64 + oo]  + bih[64 + oo];
      float hr = s_gig[e][96 + oo]  + bhh[oo];
      float hz = s_gig[e][128 + oo] + bhh[32 + oo];
      float hn = s_gig[e][160 + oo] + bhh[64 + oo];
      float r  = sigmoid_f(ir + hr);
      float zz = sigmoid_f(iz + hz);
      float n  = tanh_f(in_ + r*hn);
      float Mn = (1.f - zz)*n + zz*s_M[e][oo];
      s_M[e][oo] = Mn;
      s_vsM[e][oo*2+1] = Mn;
    }
    __syncthreads();
  }

  // ---- epilogue: Mw = sigmoid(M @ ans_w.T + ans_b); out = vs . Mw ----
  #pragma unroll
  for (int e = 0; e < 2; ++e){
    const int cc = (tid & 7) * 4;
    const int rr = tid >> 3;
    float4 m4 = *(const float4*)&s_M[e][cc];
    float4 aw = *(const float4*)(ans_w + (size_t)rr*32 + cc);
    float a = aw.x*m4.x + aw.y*m4.y + aw.z*m4.z + aw.w*m4.w;
    a += __shfl_xor(a,1); a += __shfl_xor(a,2); a += __shfl_xor(a,4);
    if ((tid & 7) == 0) s_zpart[e][rr] = sigmoid_f(a + ans_b[rr]);
  }
  __syncthreads();
  if (tid < 64){
    int e = tid >> 5, oo = tid & 31;
    float val = s_vsM[e][oo*2+0] * s_zpart[e][oo];
    #pragma unroll
    for (int s = 16; s > 0; s >>= 1) val += __shfl_xor(val, s);
    if (oo == 0) out[e ? eB : eA] = val;
  }
}

extern "C" void kernel_launch(void* const* d_in, const int* in_sizes, int n_in,
                              void* d_out, int out_size, void* d_ws, size_t ws_size,
                              hipStream_t stream) {
  const int*   h_i          = (const int*)  d_in[0];
  const int*   R_i          = (const int*)  d_in[1];
  const int*   t_i          = (const int*)  d_in[2];
  const int*   v_i          = (const int*)  d_in[3];
  const float* entity_emb   = (const float*)d_in[4];
  const float* relation_emb = (const float*)d_in[5];
  const float* agg_w1       = (const float*)d_in[6];
  const float* agg_b1       = (const float*)d_in[7];
  const float* agg_w2       = (const float*)d_in[8];
  const float* agg_b2       = (const float*)d_in[9];   // softmax-invariant, dropped
  const float* gru_w_ih     = (const float*)d_in[10];
  const float* gru_w_hh     = (const float*)d_in[11];
  const float* gru_b_ih     = (const float*)d_in[12];
  const float* gru_b_hh     = (const float*)d_in[13];
  const float* ans_w        = (const float*)d_in[14];
  const float* ans_b        = (const float*)d_in[15];
  (void)agg_b2;
  float* outp = (float*)d_out;

  const int batch = in_sizes[3];
  const int grid  = (batch + 1) / 2;
  ripple_fused<<<grid, 256, 0, stream>>>(
      h_i, R_i, t_i, v_i, entity_emb, relation_emb,
      agg_w1, agg_b1, agg_w2, agg_b2,
      gru_w_ih, gru_w_hh, gru_b_ih, gru_b_hh,
      ans_w, ans_b, outp, batch);
}

// Round 13
// 40.983 us; speedup vs baseline: 1.1790x; 1.1790x over previous
//
#include <hip/hip_runtime.h>
#include <hip/hip_bf16.h>

// RippleNetPlus fused — 1 block (256 thr) per TWO batch elements.
// DIM=32, HOP=2, MEM=32, BATCH=2048 -> grid 1024 = exactly 4 blocks/CU.
//
// Round 13: R11 (42.2us verified) + two chain-shortening micro-opts.
// R12 lesson: the allocator caps in-flight loads (~56-64 VGPR) regardless of
// occupancy headroom -> widening parallel streams per iteration fails.
// Instead remove latency from the serial chain without adding live values:
//  - phase A: pipeline the 4 index ints one iteration ahead (+4 regs);
//    every iteration's 18 loads (16 rv + 2 hv) are address-ready at the top,
//    cutting the ~200cy idx->load dependency from each of 8 iterations.
//  - hoist hop-invariant bv B-fragments out of the hop loop (8 fewer
//    ds_read_b128; +16 regs, free at 4 blocks/CU).
// Everything else byte-identical to R11.

#define NHOP 2

typedef __attribute__((ext_vector_type(4)))  float f32x4;
typedef __attribute__((ext_vector_type(8)))  short bf16x8s;
typedef __attribute__((ext_vector_type(4)))  int   i32x4;

__device__ __forceinline__ float sigmoid_f(float x){ return 1.0f/(1.0f+__expf(-x)); }
__device__ __forceinline__ float tanh_f(float x){
  float e = __expf(2.0f*x);
  return 1.0f - 2.0f/(e + 1.0f);
}
__device__ __forceinline__ unsigned pk_bf16(float lo, float hi){
  __hip_bfloat162 h = __float22bfloat162_rn(make_float2(lo, hi));
  return *reinterpret_cast<unsigned*>(&h);
}
__device__ __forceinline__ float bfly8(float p[8], bool bb4, bool bb2, bool bb1){
  #pragma unroll
  for (int k = 0; k < 4; ++k){
    float send = bb4 ? p[k] : p[k+4];
    float t = __shfl_xor(send, 4);
    p[k] = (bb4 ? p[k+4] : p[k]) + t;
  }
  #pragma unroll
  for (int k = 0; k < 2; ++k){
    float send = bb2 ? p[k] : p[k+2];
    float t = __shfl_xor(send, 2);
    p[k] = (bb2 ? p[k+2] : p[k]) + t;
  }
  float send = bb1 ? p[0] : p[1];
  float t = __shfl_xor(send, 1);
  return (bb1 ? p[1] : p[0]) + t;
}

__global__ __launch_bounds__(256) void ripple_fused(
    const int* __restrict__ h_i, const int* __restrict__ R_i, const int* __restrict__ t_i,
    const int* __restrict__ v_i,
    const float* __restrict__ entity_emb, const float* __restrict__ relation_emb,
    const float* __restrict__ agg_w1, const float* __restrict__ agg_b1,
    const float* __restrict__ agg_w2, const float* __restrict__ agg_b2,
    const float* __restrict__ gru_w_ih, const float* __restrict__ gru_w_hh,
    const float* __restrict__ gru_b_ih, const float* __restrict__ gru_b_hh,
    const float* __restrict__ ans_w, const float* __restrict__ ans_b,
    float* __restrict__ out, int batch)
{
  __shared__ __align__(16) int   s_bfrag[8*64*4];     // 8 KB   shared B-frags
  __shared__ __align__(16) float s_rhA[2][2][32*33];  // 16.5KB [elem][hop] stride-33
  __shared__ __align__(16) float s_vsM[2][64];        // [elem][i*2+{vs,M}]
  __shared__ __align__(16) float s_zpart[2][64];      // [elem][ot*32+m]
  __shared__ __align__(16) float s_opart[2][4*32];    // [elem][w][o]
  __shared__ __align__(16) float s_M[2][32];
  __shared__ __align__(16) float s_gig[2][192];       // [elem] gi[0:96] gh[96:192]

  const int bid = blockIdx.x;
  const int eA  = bid*2;
  const int eB  = (eA + 1 < batch) ? eA + 1 : eA;
  const int tid = threadIdx.x;
  const int g   = tid >> 5;   // group 0..7
  const int o   = tid & 31;
  const int l   = tid & 63;   // lane
  const int w   = tid >> 6;   // wave 0..3
  const int c   = o & 7;
  const int r_  = o >> 3;
  const bool bb4 = (c & 4) != 0;
  const bool bb2 = (c & 2) != 0;
  const bool bb1 = (c & 1) != 0;

  // ---- init: stage B-fragments (16x16x32 layout; same as R10/R11) ----
  #pragma unroll
  for (int k = 0; k < 2; ++k){
    int s  = tid + k*256;           // 0..511
    int f  = s >> 6, li = s & 63;
    int x  = f >> 1, otf = f & 1;
    const float* src = agg_w1 + (otf*16 + (li & 15))*128 + x*32 + ((li >> 4) & 3)*8;
    float4 f0 = *(const float4*)src;
    float4 f1 = *(const float4*)(src + 4);
    *(int4*)&s_bfrag[s*4] = make_int4((int)pk_bf16(f0.x, f0.y), (int)pk_bf16(f0.z, f0.w),
                                      (int)pk_bf16(f1.x, f1.y), (int)pk_bf16(f1.z, f1.w));
  }
  if (tid < 64){
    int e  = tid >> 5, oo = tid & 31;
    float v = entity_emb[(size_t)v_i[e ? eB : eA]*32 + oo];
    s_vsM[e][oo*2+0] = v; s_vsM[e][oo*2+1] = v; s_M[e][oo] = v;
  }

  // ---- phase A (both hops x both elems): dual-chain Rh gather with
  //      index loads pipelined one iteration ahead ----
  {
    const int iA = c*4 + r_;
    const int bgm = g*4;
    int rAc = R_i[(eA*NHOP + 0)*32 + bgm];
    int hAc = h_i[(eA*NHOP + 0)*32 + bgm];
    int rBc = R_i[(eB*NHOP + 0)*32 + bgm];
    int hBc = h_i[(eB*NHOP + 0)*32 + bgm];
    #pragma unroll 1
    for (int it = 0; it < 8; ++it){
      const int hp = it >> 2;
      const int m  = bgm + (it & 3);
      // prefetch next iteration's indices (issued before the heavy body)
      int rAn = rAc, hAn = hAc, rBn = rBc, hBn = hBc;
      if (it < 7){
        const int nhp = (it + 1) >> 2;
        const int nm  = bgm + ((it + 1) & 3);
        rAn = R_i[(eA*NHOP + nhp)*32 + nm];
        hAn = h_i[(eA*NHOP + nhp)*32 + nm];
        rBn = R_i[(eB*NHOP + nhp)*32 + nm];
        hBn = h_i[(eB*NHOP + nhp)*32 + nm];
      }
      const float* RbA = relation_emb + (size_t)rAc*1024;
      const float* RbB = relation_emb + (size_t)rBc*1024;
      float4 hvA = *(const float4*)(entity_emb + (size_t)hAc*32 + c*4);
      float4 hvB = *(const float4*)(entity_emb + (size_t)hBc*32 + c*4);
      float pA[8], pB[8];
      #pragma unroll
      for (int q = 0; q < 8; ++q){
        float4 rv = *(const float4*)(RbA + q*128 + o*4);
        pA[q] = rv.x*hvA.x + rv.y*hvA.y + rv.z*hvA.z + rv.w*hvA.w;
      }
      #pragma unroll
      for (int q = 0; q < 8; ++q){
        float4 rv = *(const float4*)(RbB + q*128 + o*4);
        pB[q] = rv.x*hvB.x + rv.y*hvB.y + rv.z*hvB.z + rv.w*hvB.w;
      }
      float a0 = bfly8(pA, bb4, bb2, bb1);
      float a1 = bfly8(pB, bb4, bb2, bb1);
      s_rhA[0][hp][m*33 + iA] = a0;
      s_rhA[1][hp][m*33 + iA] = a1;
      rAc = rAn; hAc = hAn; rBc = rBn; hBc = hBn;
    }
  }
  __syncthreads();

  // per-wave tile coords (phase B) + hop-invariant B-fragments in registers
  const int mt  = w >> 1, ot = w & 1;
  const int col = l & 15;
  const int kg  = l >> 4;
  const float b1o = agg_b1[ot*16 + col];
  const float w2o = agg_w2[ot*16 + col];
  i32x4 bv[4];
  #pragma unroll
  for (int x = 0; x < 4; ++x)
    bv[x] = *(const i32x4*)&s_bfrag[((x*2 + ot)*64 + l)*4];

  for (int hop = 0; hop < NHOP; ++hop){
    // ---- t-row prefetch for both elements ----
    float tvA[4], tvB[4];
    #pragma unroll
    for (int ml = 0; ml < 4; ++ml){
      tvA[ml] = entity_emb[(size_t)t_i[(eA*NHOP + hop)*32 + g*4 + ml]*32 + o];
      tvB[ml] = entity_emb[(size_t)t_i[(eB*NHOP + hop)*32 + g*4 + ml]*32 + o];
    }

    // ---- phase B: wave tile via mfma_16x16x32, both elements ----
    {
      #pragma unroll
      for (int e = 0; e < 2; ++e){
        const float* rp = &s_rhA[e][hop][(mt*16 + col)*33 + kg*8];
        float4 q0 = *(const float4*)(rp);
        float4 q1 = *(const float4*)(rp + 4);
        float rh[8] = {q0.x,q0.y,q0.z,q0.w,q1.x,q1.y,q1.z,q1.w};
        unsigned aw[4][4];
        #pragma unroll
        for (int q = 0; q < 4; ++q){
          int i0 = kg*8 + 2*q;
          float2 vm0 = *(const float2*)&s_vsM[e][i0*2];
          float2 vm1 = *(const float2*)&s_vsM[e][(i0+1)*2];
          float e0 = rh[2*q], e1 = rh[2*q+1];
          aw[0][q] = pk_bf16(e0*vm0.x,        e1*vm1.x);
          aw[1][q] = pk_bf16(e0*vm0.y,        e1*vm1.y);
          aw[2][q] = pk_bf16(fabsf(e0-vm0.x), fabsf(e1-vm1.x));
          aw[3][q] = pk_bf16(fabsf(e0-vm0.y), fabsf(e1-vm1.y));
        }
        f32x4 acc = {0.f, 0.f, 0.f, 0.f};
        #pragma unroll
        for (int x = 0; x < 4; ++x){
          i32x4 av = {(int)aw[x][0], (int)aw[x][1], (int)aw[x][2], (int)aw[x][3]};
          acc = __builtin_amdgcn_mfma_f32_16x16x32_bf16(
                  __builtin_bit_cast(bf16x8s, av),
                  __builtin_bit_cast(bf16x8s, bv[x]), acc, 0, 0, 0);
        }
        float v[4];
        #pragma unroll
        for (int r = 0; r < 4; ++r) v[r] = tanh_f(acc[r] + b1o) * w2o;
        const bool b3 = (l & 8) != 0;
        #pragma unroll
        for (int k = 0; k < 2; ++k){
          float send = b3 ? v[k] : v[k+2];
          float tt = __shfl_xor(send, 8);
          v[k] = (b3 ? v[k+2] : v[k]) + tt;
        }
        const bool b2_ = (l & 4) != 0;
        {
          float send = b2_ ? v[0] : v[1];
          float tt = __shfl_xor(send, 4);
          v[0] = (b2_ ? v[1] : v[0]) + tt;
        }
        v[0] += __shfl_xor(v[0], 2);
        v[0] += __shfl_xor(v[0], 1);
        if ((l & 3) == 0){
          int m_local = kg*4 + ((l >> 3) & 1)*2 + ((l >> 2) & 1);
          s_zpart[e][ot*32 + mt*16 + m_local] = v[0];
        }
      }
    }
    __syncthreads();

    // ---- phase C: softmax (all lanes) + weighted-t, both elements;
    //      in-wave cross-group combine via shfl_xor(32) -> 4 partials ----
    #pragma unroll
    for (int e = 0; e < 2; ++e){
      float z  = s_zpart[e][o] + s_zpart[e][32 + o];
      float mx = z;
      #pragma unroll
      for (int s = 16; s > 0; s >>= 1) mx = fmaxf(mx, __shfl_xor(mx, s));
      float ex = __expf(z - mx);
      float sm = ex;
      #pragma unroll
      for (int s = 16; s > 0; s >>= 1) sm += __shfl_xor(sm, s);
      float gval = ex / sm;
      float po = 0.f;
      #pragma unroll
      for (int ml = 0; ml < 4; ++ml)
        po += __shfl(gval, g*4 + ml) * (e == 0 ? tvA[ml] : tvB[ml]);
      po += __shfl_xor(po, 32);
      if (l < 32) s_opart[e][w*32 + o] = po;
    }
    __syncthreads();

    // ---- phase D: GRU gates, weights loaded once for both elements ----
    {
      const int cc = (tid & 7) * 4;
      const int rr = tid >> 3;
      float4 oA = make_float4(0,0,0,0), oB = make_float4(0,0,0,0);
      #pragma unroll
      for (int gg = 0; gg < 4; ++gg){
        float4 ta = *(const float4*)&s_opart[0][gg*32 + cc];
        float4 tb = *(const float4*)&s_opart[1][gg*32 + cc];
        oA.x += ta.x; oA.y += ta.y; oA.z += ta.z; oA.w += ta.w;
        oB.x += tb.x; oB.y += tb.y; oB.z += tb.z; oB.w += tb.w;
      }
      float4 mA = *(const float4*)&s_M[0][cc];
      float4 mB = *(const float4*)&s_M[1][cc];
      #pragma unroll
      for (int k = 0; k < 3; ++k){
        int row = k*32 + rr;
        float4 wi = *(const float4*)(gru_w_ih + ((size_t)hop*96 + row)*32 + cc);
        float4 wh = *(const float4*)(gru_w_hh + ((size_t)hop*96 + row)*32 + cc);
        float aiA = wi.x*oA.x + wi.y*oA.y + wi.z*oA.z + wi.w*oA.w;
        float ahA = wh.x*mA.x + wh.y*mA.y + wh.z*mA.z + wh.w*mA.w;
        float aiB = wi.x*oB.x + wi.y*oB.y + wi.z*oB.z + wi.w*oB.w;
        float ahB = wh.x*mB.x + wh.y*mB.y + wh.z*mB.z + wh.w*mB.w;
        aiA += __shfl_xor(aiA,1); aiA += __shfl_xor(aiA,2); aiA += __shfl_xor(aiA,4);
        ahA += __shfl_xor(ahA,1); ahA += __shfl_xor(ahA,2); ahA += __shfl_xor(ahA,4);
        aiB += __shfl_xor(aiB,1); aiB += __shfl_xor(aiB,2); aiB += __shfl_xor(aiB,4);
        ahB += __shfl_xor(ahB,1); ahB += __shfl_xor(ahB,2); ahB += __shfl_xor(ahB,4);
        if ((tid & 7) == 0){
          s_gig[0][row]      = aiA;
          s_gig[0][96 + row] = ahA;
          s_gig[1][row]      = aiB;
          s_gig[1][96 + row] = ahB;
        }
      }
    }
    __syncthreads();

    // ---- phase E: GRU update — lanes 0-31 elem A, 32-63 elem B ----
    if (tid < 64){
      int e = tid >> 5, oo = tid & 31;
      const float* bih = gru_b_ih + hop*96;
      const float* bhh = gru_b_hh + hop*96;
      float ir = s_gig[e][oo]       + bih[oo];
      float iz = s_gig[e][32 + oo]  + bih[32 + oo];
      float in_= s_gig[e][64 + oo]  + bih[64 + oo];
      float hr = s_gig[e][96 + oo]  + bhh[oo];
      float hz = s_gig[e][128 + oo] + bhh[32 + oo];
      float hn = s_gig[e][160 + oo] + bhh[64 + oo];
      float r  = sigmoid_f(ir + hr);
      float zz = sigmoid_f(iz + hz);
      float n  = tanh_f(in_ + r*hn);
      float Mn = (1.f - zz)*n + zz*s_M[e][oo];
      s_M[e][oo] = Mn;
      s_vsM[e][oo*2+1] = Mn;
    }
    __syncthreads();
  }

  // ---- epilogue: Mw = sigmoid(M @ ans_w.T + ans_b); out = vs . Mw ----
  #pragma unroll
  for (int e = 0; e < 2; ++e){
    const int cc = (tid & 7) * 4;
    const int rr = tid >> 3;
    float4 m4 = *(const float4*)&s_M[e][cc];
    float4 aw = *(const float4*)(ans_w + (size_t)rr*32 + cc);
    float a = aw.x*m4.x + aw.y*m4.y + aw.z*m4.z + aw.w*m4.w;
    a += __shfl_xor(a,1); a += __shfl_xor(a,2); a += __shfl_xor(a,4);
    if ((tid & 7) == 0) s_zpart[e][rr] = sigmoid_f(a + ans_b[rr]);
  }
  __syncthreads();
  if (tid < 64){
    int e = tid >> 5, oo = tid & 31;
    float val = s_vsM[e][oo*2+0] * s_zpart[e][oo];
    #pragma unroll
    for (int s = 16; s > 0; s >>= 1) val += __shfl_xor(val, s);
    if (oo == 0) out[e ? eB : eA] = val;
  }
}

extern "C" void kernel_launch(void* const* d_in, const int* in_sizes, int n_in,
                              void* d_out, int out_size, void* d_ws, size_t ws_size,
                              hipStream_t stream) {
  const int*   h_i          = (const int*)  d_in[0];
  const int*   R_i          = (const int*)  d_in[1];
  const int*   t_i          = (const int*)  d_in[2];
  const int*   v_i          = (const int*)  d_in[3];
  const float* entity_emb   = (const float*)d_in[4];
  const float* relation_emb = (const float*)d_in[5];
  const float* agg_w1       = (const float*)d_in[6];
  const float* agg_b1       = (const float*)d_in[7];
  const float* agg_w2       = (const float*)d_in[8];
  const float* agg_b2       = (const float*)d_in[9];   // softmax-invariant, dropped
  const float* gru_w_ih     = (const float*)d_in[10];
  const float* gru_w_hh     = (const float*)d_in[11];
  const float* gru_b_ih     = (const float*)d_in[12];
  const float* gru_b_hh     = (const float*)d_in[13];
  const float* ans_w        = (const float*)d_in[14];
  const float* ans_b        = (const float*)d_in[15];
  (void)agg_b2;
  float* outp = (float*)d_out;

  const int batch = in_sizes[3];
  const int grid  = (batch + 1) / 2;
  ripple_fused<<<grid, 256, 0, stream>>>(
      h_i, R_i, t_i, v_i, entity_emb, relation_emb,
      agg_w1, agg_b1, agg_w2, agg_b2,
      gru_w_ih, gru_w_hh, gru_b_ih, gru_b_hh,
      ans_w, ans_b, outp, batch);
}